// Round 19
// baseline (250.903 us; speedup 1.0000x reference)
//
#include <hip/hip_runtime.h>
#include <hip/hip_fp16.h>

#define NN 100000
#define NE 1600000
// IN_FEAT=128, N_HEADS=8, OUT_FEAT=16, H*F=128

static __device__ __forceinline__ unsigned short f32_to_bf16_rne(float x) {
    unsigned int u = __float_as_uint(x);
    u += 0x7fff + ((u >> 16) & 1);   // round-to-nearest-even
    return (unsigned short)(u >> 16);
}
static __device__ __forceinline__ float bf16_to_f32(unsigned int bits16) {
    return __uint_as_float(bits16 << 16);
}

// ---------------- Kernel 1: fused proj-GEMM + scores, 128-row tile ----------------
// k-major X staging (broadcast b128 reads, conflict-free — r13-measured pattern),
// 16 contiguous rows/thread -> 64 FMA : 5 LDS-b128 per k (VALU-bound).
// Also zeroes denom_h/out_h rows inline (replaces two hipMemsetAsync launches).
__global__ __launch_bounds__(256) void gemm_score_kernel(const float* __restrict__ x,
                                                         const float* __restrict__ W,
                                                         const float* __restrict__ a_src,
                                                         const float* __restrict__ a_tgt,
                                                         unsigned short* __restrict__ projT,
                                                         unsigned short* __restrict__ s_src_b,
                                                         unsigned short* __restrict__ s_tgt_b,
                                                         __half* __restrict__ denom_h,
                                                         __half* __restrict__ out_h) {
    __shared__ float sXT[32][128];  // k-major: sXT[k][row]
    __shared__ float sW[32][128];
    const int t = threadIdx.x;
    const int n0 = blockIdx.x * 128;
    const int c0 = (t & 31) * 4;    // head h=c0>>4, first feat f0=c0&15
    const int r0 = t >> 5;          // 0..7; rows r0*16 .. r0*16+15
    float acc[16][4];
#pragma unroll
    for (int i = 0; i < 16; i++)
#pragma unroll
        for (int j = 0; j < 4; j++) acc[i][j] = 0.f;

    for (int kt = 0; kt < 128; kt += 32) {
        // stage X tile transposed: 128 rows x 32 k = 1024 float4
#pragma unroll
        for (int p = 0; p < 4; p++) {
            int idx = t + p * 256;          // 0..1023
            int r = idx >> 3;               // 0..127
            int kk = idx & 7;
            float4 v = make_float4(0.f, 0.f, 0.f, 0.f);
            int n = n0 + r;
            if (n < NN) v = *reinterpret_cast<const float4*>(&x[(size_t)n * 128 + kt + kk * 4]);
            sXT[kk * 4 + 0][r] = v.x;
            sXT[kk * 4 + 1][r] = v.y;
            sXT[kk * 4 + 2][r] = v.z;
            sXT[kk * 4 + 3][r] = v.w;
        }
        // stage W tile: 32x128
#pragma unroll
        for (int p = 0; p < 4; p++) {
            int idx = t + p * 256;
            int kr = idx >> 5;
            int c4 = idx & 31;
            float4 v = *reinterpret_cast<const float4*>(&W[(size_t)(kt + kr) * 128 + c4 * 4]);
            *reinterpret_cast<float4*>(&sW[kr][c4 * 4]) = v;
        }
        __syncthreads();
#pragma unroll
        for (int k = 0; k < 32; k++) {
            float4 xa = *reinterpret_cast<const float4*>(&sXT[k][r0 * 16]);
            float4 xb = *reinterpret_cast<const float4*>(&sXT[k][r0 * 16 + 4]);
            float4 xc = *reinterpret_cast<const float4*>(&sXT[k][r0 * 16 + 8]);
            float4 xd = *reinterpret_cast<const float4*>(&sXT[k][r0 * 16 + 12]);
            float4 wv = *reinterpret_cast<const float4*>(&sW[k][c0]);
            float xs[16] = {xa.x, xa.y, xa.z, xa.w, xb.x, xb.y, xb.z, xb.w,
                            xc.x, xc.y, xc.z, xc.w, xd.x, xd.y, xd.z, xd.w};
#pragma unroll
            for (int i = 0; i < 16; i++) {
                acc[i][0] += xs[i] * wv.x;
                acc[i][1] += xs[i] * wv.y;
                acc[i][2] += xs[i] * wv.z;
                acc[i][3] += xs[i] * wv.w;
            }
        }
        __syncthreads();
    }
    const int h  = c0 >> 4;
    const int f0 = c0 & 15;
    const float aS0 = a_src[c0], aS1 = a_src[c0 + 1], aS2 = a_src[c0 + 2], aS3 = a_src[c0 + 3];
    const float aT0 = a_tgt[c0], aT1 = a_tgt[c0 + 1], aT2 = a_tgt[c0 + 2], aT3 = a_tgt[c0 + 3];
#pragma unroll
    for (int i = 0; i < 16; i++) {
        int n = n0 + r0 * 16 + i;
        if (n < NN) {
            unsigned short* pT = &projT[(size_t)n * 128];
#pragma unroll
            for (int j = 0; j < 4; j++) pT[(f0 + j) * 8 + h] = f32_to_bf16_rne(acc[i][j]);
            float ss = acc[i][0] * aS0 + acc[i][1] * aS1 + acc[i][2] * aS2 + acc[i][3] * aS3;
            float st = acc[i][0] * aT0 + acc[i][1] * aT1 + acc[i][2] * aT2 + acc[i][3] * aT3;
            ss += __shfl_xor(ss, 1);
            ss += __shfl_xor(ss, 2);
            st += __shfl_xor(st, 1);
            st += __shfl_xor(st, 2);
            if ((t & 3) == 0) {
                s_src_b[(size_t)n * 8 + h] = f32_to_bf16_rne(ss);
                s_tgt_b[(size_t)n * 8 + h] = f32_to_bf16_rne(st);
            }
            if ((t & 31) == 0) {   // one lane per node: zero the f16 accumulators
                *reinterpret_cast<uint4*>(&denom_h[(size_t)n * 8])    = make_uint4(0, 0, 0, 0);
                *reinterpret_cast<uint4*>(&out_h[(size_t)n * 16])     = make_uint4(0, 0, 0, 0);
                *reinterpret_cast<uint4*>(&out_h[(size_t)n * 16 + 8]) = make_uint4(0, 0, 0, 0);
            }
        }
    }
}

// ---------------- Kernel 2: denom via packed-f16 HW atomics (frozen from r18) ----------------
__global__ __launch_bounds__(256) void denom_kernel(const int* __restrict__ src,
                                                    const int* __restrict__ tgt,
                                                    const unsigned short* __restrict__ s_src_b,
                                                    const unsigned short* __restrict__ s_tgt_b,
                                                    __half* __restrict__ denom_h,
                                                    unsigned short* __restrict__ exb) {
    int gid = blockIdx.x * blockDim.x + threadIdx.x;
    int e = gid >> 2;
    if (e >= NE) return;
    int h0 = (gid & 3) * 2;
    int s = src[e], t = tgt[e];
    unsigned int ssp = *reinterpret_cast<const unsigned int*>(&s_src_b[(size_t)s * 8 + h0]);
    unsigned int stp = *reinterpret_cast<const unsigned int*>(&s_tgt_b[(size_t)t * 8 + h0]);
    float v0 = bf16_to_f32(ssp & 0xffffu) + bf16_to_f32(stp & 0xffffu);
    float v1 = bf16_to_f32(ssp >> 16) + bf16_to_f32(stp >> 16);
    v0 = v0 >= 0.f ? v0 : 0.2f * v0;
    v1 = v1 >= 0.f ? v1 : 0.2f * v1;
    float ex0 = expf(v0), ex1 = expf(v1);
    unsigned int pk = (unsigned int)f32_to_bf16_rne(ex0) | ((unsigned int)f32_to_bf16_rne(ex1) << 16);
    *reinterpret_cast<unsigned int*>(&exb[(size_t)e * 8 + h0]) = pk;
    unsafeAtomicAdd(reinterpret_cast<__half2*>(&denom_h[(size_t)t * 8 + h0]),
                    __floats2half2_rn(ex0, ex1));
}

// ---------------- Kernel 3: aggregate via packed-f16 HW atomics (frozen from r18) ----------------
__global__ __launch_bounds__(256) void aggregate_kernel(const int* __restrict__ src,
                                                        const int* __restrict__ tgt,
                                                        const __half* __restrict__ denom_h,
                                                        const unsigned short* __restrict__ exb,
                                                        const unsigned short* __restrict__ projT,
                                                        __half* __restrict__ out_h) {
    int gid = blockIdx.x * blockDim.x + threadIdx.x;
    int e = gid >> 3;
    if (e >= NE) return;
    int j = gid & 7;       // head j; features 2j, 2j+1
    int s = src[e], t = tgt[e];
    float ex = bf16_to_f32(exb[(size_t)e * 8 + j]);
    float dj = __half2float(denom_h[(size_t)t * 8 + j]);
    float alpha = ex / (dj + 1e-16f);
    uint4 va = *reinterpret_cast<const uint4*>(&projT[(size_t)s * 128 + (2 * j) * 8]);
    uint4 vb = *reinterpret_cast<const uint4*>(&projT[(size_t)s * 128 + (2 * j + 1) * 8]);
    float m0 = 0.f, m1 = 0.f;
#pragma unroll
    for (int k = 0; k < 8; k++) {
        float ak = __shfl(alpha, k, 8);
        unsigned int wa = (k & 1) ? ((&va.x)[k >> 1] >> 16) : ((&va.x)[k >> 1] & 0xffffu);
        unsigned int wb = (k & 1) ? ((&vb.x)[k >> 1] >> 16) : ((&vb.x)[k >> 1] & 0xffffu);
        m0 += ak * bf16_to_f32(wa);
        m1 += ak * bf16_to_f32(wb);
    }
    unsafeAtomicAdd(reinterpret_cast<__half2*>(&out_h[(size_t)t * 16 + 2 * j]),
                    __floats2half2_rn(m0 * 0.125f, m1 * 0.125f));
}

// ---------------- Kernel 4: bias + softmax over 16 features ----------------
__global__ __launch_bounds__(256) void softmax_kernel(const __half* __restrict__ out_h,
                                                      const float* __restrict__ bias,
                                                      float* __restrict__ out) {
    int gid = blockIdx.x * blockDim.x + threadIdx.x;
    int n = gid >> 4;
    int lane = gid & 15;
    if (n >= NN) return;
    float v = __half2float(out_h[(size_t)n * 16 + lane]) + bias[lane];
    float mx = v;
#pragma unroll
    for (int m = 1; m < 16; m <<= 1) mx = fmaxf(mx, __shfl_xor(mx, m, 64));
    float ex = expf(v - mx);
    float sum = ex;
#pragma unroll
    for (int m = 1; m < 16; m <<= 1) sum += __shfl_xor(sum, m, 64);
    out[(size_t)n * 16 + lane] = ex / sum;
}

extern "C" void kernel_launch(void* const* d_in, const int* in_sizes, int n_in,
                              void* d_out, int out_size, void* d_ws, size_t ws_size,
                              hipStream_t stream) {
    const float* x     = (const float*)d_in[0];
    const int*   ei    = (const int*)d_in[1];
    const float* W     = (const float*)d_in[2];
    const float* a_src = (const float*)d_in[3];
    const float* a_tgt = (const float*)d_in[4];
    const float* bias  = (const float*)d_in[5];
    float* out = (float*)d_out;

    const int* src = ei;            // edge_index[0]
    const int* tgt = ei + NE;       // edge_index[1]

    char* ws = (char*)d_ws;
    size_t off = 0;
    auto alloc = [&](size_t bytes) {
        char* p = ws + off;
        off += (bytes + 255) & ~(size_t)255;
        return p;
    };
    unsigned short* projT   = (unsigned short*)alloc((size_t)NN * 128 * 2); // 25.6 MB bf16, f-major
    unsigned short* exb     = (unsigned short*)alloc((size_t)NE * 8 * 2);   // 25.6 MB bf16 ex[e][h]
    unsigned short* s_src_b = (unsigned short*)alloc((size_t)NN * 8 * 2);   // 1.6 MB
    unsigned short* s_tgt_b = (unsigned short*)alloc((size_t)NN * 8 * 2);   // 1.6 MB
    __half*         denom_h = (__half*)alloc((size_t)NN * 8 * 2);           // 1.6 MB f16
    __half*         out_h   = (__half*)alloc((size_t)NN * 16 * 2);          // 3.2 MB f16

    // accumulator zeroing folded into gemm_score_kernel (runs first, same stream)

    gemm_score_kernel<<<(NN + 127) / 128, 256, 0, stream>>>(x, W, a_src, a_tgt, projT,
                                                            s_src_b, s_tgt_b, denom_h, out_h);
    denom_kernel<<<((size_t)NE * 4 + 255) / 256, 256, 0, stream>>>(src, tgt, s_src_b, s_tgt_b,
                                                                   denom_h, exb);
    aggregate_kernel<<<((size_t)NE * 8 + 255) / 256, 256, 0, stream>>>(src, tgt, denom_h, exb,
                                                                       projT, out_h);
    softmax_kernel<<<(NN * 16 + 255) / 256, 256, 0, stream>>>(out_h, bias, out);
}